// Round 3
// baseline (511.171 us; speedup 1.0000x reference)
//
#include <hip/hip_runtime.h>
#include <hip/hip_bf16.h>

#define B_DIM 64
#define T_DIM 2048
#define D_DIM 512
#define U_DIM 512

typedef __bf16 bf16x8 __attribute__((ext_vector_type(8)));
typedef float  f32x4  __attribute__((ext_vector_type(4)));
typedef unsigned int u32;

// async global->LDS, 16B per lane (global_load_lds_dwordx4)
__device__ __forceinline__ void gl_lds16(const __bf16* g, __bf16* l) {
    __builtin_amdgcn_global_load_lds(
        (const __attribute__((address_space(1))) u32*)g,
        (__attribute__((address_space(3))) u32*)l,
        16, 0, 0);
}

// ---------------------------------------------------------------------------
// W1 [D][U] fp32 -> w1c bf16 chunk-plane layout:
//   w1c[((d>>3)*512 + u)*8 + (d&7)]
// so that each BK=32 K-block is a flat 32 KiB image matching the LDS tile.
// Grid 128 x 256. Reads coalesced over u; writes contiguous 16B/thread.
// ---------------------------------------------------------------------------
__global__ void w1c_kernel(const float* __restrict__ W1w, __bf16* __restrict__ w1c) {
    int idx = blockIdx.x * 256 + threadIdx.x;   // 32768 = 512u * 64 octets
    int u   = idx & 511;
    int oct = idx >> 9;                          // d = oct*8 + j
    bf16x8 w;
    #pragma unroll
    for (int j = 0; j < 8; ++j)
        w[j] = (__bf16)W1w[(oct * 8 + j) * U_DIM + u];
    *reinterpret_cast<bf16x8*>(&w1c[(oct * 512 + (u ^ 0)) * 8]) = w;
}

// ---------------------------------------------------------------------------
// hp[b][u] = W1_b[u] + W2_b[u] + hidden[b,:] @ W2[:,u]. Grid (B,2), block 256.
// ---------------------------------------------------------------------------
__global__ void hproj_kernel(const float* __restrict__ hidden,
                             const float* __restrict__ W2w,
                             const float* __restrict__ W2b,
                             const float* __restrict__ W1b,
                             float* __restrict__ hp) {
    int b = blockIdx.x;
    int u = blockIdx.y * 256 + threadIdx.x;
    float acc = W2b[u] + W1b[u];
    const float* hrow = hidden + b * D_DIM;
    #pragma unroll 8
    for (int d = 0; d < D_DIM; ++d)
        acc = fmaf(hrow[d], W2w[d * U_DIM + u], acc);
    hp[b * U_DIM + u] = acc;
}

// ---------------------------------------------------------------------------
// scores[row] = sum_{u<512} tanh(features[row,:]@W1[:,u] + hp[b,u]) * Vw[u]
// One block = 64 rows x ALL 512 u (features read ONCE). BK=32.
// LDS chunk-plane layout: plane c holds [rows][8 k] with 16B rows ->
// fragment ds_read_b128 bank = 4*row mod 32 = 2-way aliasing = free,
// AND staging is contiguous so global_load_lds works.
// Grid 2048, block 256 (4 waves; wave wn covers u in [wn*128, wn*128+128)).
// ---------------------------------------------------------------------------
__global__ __launch_bounds__(256, 2) void score_kernel(
        const float*  __restrict__ features,
        const __bf16* __restrict__ w1c,
        const float*  __restrict__ hp,
        const float*  __restrict__ Vw,
        float*        __restrict__ scores) {
    __shared__ __align__(16) __bf16 Bs[4 * 512 * 8];   // 32 KiB: [chunk][u][8]
    __shared__ __align__(16) __bf16 As[4 * 64 * 8];    //  4 KiB: [chunk][row][8]
    __shared__ float red[4 * 64];

    const int tid  = threadIdx.x;
    const int row0 = blockIdx.x * 64;          // flattened (b,t) base
    const int b    = row0 >> 11;

    const int wn   = tid >> 6;                 // wave 0..3
    const int lane = tid & 63;
    const int l16  = lane & 15;
    const int quad = lane >> 4;

    f32x4 acc[4][8];
    #pragma unroll
    for (int i = 0; i < 4; ++i)
        #pragma unroll
        for (int j = 0; j < 8; ++j)
            acc[i][j] = (f32x4)0.0f;

    // A staging: thread = (plane p = tid>>6, row r = tid&63); 8 k-elems each.
    const float* ag = features + (size_t)(row0 + (tid & 63)) * D_DIM + (tid >> 6) * 8;
    __bf16* as_dst = &As[tid * 8];

    for (int ko = 0; ko < 16; ++ko) {          // 16 x BK=32
        // ---- A: issue global loads FIRST (HBM latency overlaps B DMA) ----
        const float4* asrc = reinterpret_cast<const float4*>(ag + ko * 32);
        float4 v0 = asrc[0];
        float4 v1 = asrc[1];

        // ---- B: flat 32 KiB async copy of this K-block's pre-swizzled image ----
        const __bf16* bsrc = w1c + ko * 16384 + tid * 8;
        #pragma unroll
        for (int c = 0; c < 8; ++c)
            gl_lds16(bsrc + c * 2048, Bs + c * 2048 + tid * 8);

        // ---- A: fp32 -> bf16, contiguous 16B store ----
        {
            bf16x8 w;
            w[0] = (__bf16)v0.x; w[1] = (__bf16)v0.y; w[2] = (__bf16)v0.z; w[3] = (__bf16)v0.w;
            w[4] = (__bf16)v1.x; w[5] = (__bf16)v1.y; w[6] = (__bf16)v1.z; w[7] = (__bf16)v1.w;
            *reinterpret_cast<bf16x8*>(as_dst) = w;
        }
        __syncthreads();

        // ---- fragments + MFMA (one 16x16x32 per (mt,nt)) ----
        bf16x8 af[4], bfr[8];
        #pragma unroll
        for (int mt = 0; mt < 4; ++mt)
            af[mt] = *reinterpret_cast<const bf16x8*>(
                &As[(quad * 64 + mt * 16 + l16) * 8]);
        #pragma unroll
        for (int nt = 0; nt < 8; ++nt)
            bfr[nt] = *reinterpret_cast<const bf16x8*>(
                &Bs[(quad * 512 + wn * 128 + nt * 16 + l16) * 8]);
        #pragma unroll
        for (int mt = 0; mt < 4; ++mt)
            #pragma unroll
            for (int nt = 0; nt < 8; ++nt)
                acc[mt][nt] = __builtin_amdgcn_mfma_f32_16x16x32_bf16(
                    af[mt], bfr[nt], acc[mt][nt], 0, 0, 0);
        __syncthreads();
    }

    // ---- epilogue: tanh(f_proj + hp) . Vw, reduce over u ----
    float hpv[8], vwv[8];
    #pragma unroll
    for (int nt = 0; nt < 8; ++nt) {
        int u = wn * 128 + nt * 16 + l16;       // C/D col = lane&15
        hpv[nt] = hp[b * U_DIM + u];
        vwv[nt] = Vw[u];
    }
    #pragma unroll
    for (int mt = 0; mt < 4; ++mt) {
        #pragma unroll
        for (int reg = 0; reg < 4; ++reg) {
            float s = 0.0f;
            #pragma unroll
            for (int nt = 0; nt < 8; ++nt) {
                float x = acc[mt][nt][reg] + hpv[nt];
                float e = exp2f(x * 2.88539008f);           // e^{2x}
                float th = 1.0f - 2.0f * __builtin_amdgcn_rcpf(e + 1.0f);
                s = fmaf(th, vwv[nt], s);
            }
            s += __shfl_xor(s, 1);
            s += __shfl_xor(s, 2);
            s += __shfl_xor(s, 4);
            s += __shfl_xor(s, 8);
            if (l16 == 0)
                red[wn * 64 + mt * 16 + quad * 4 + reg] = s;  // C/D row = quad*4+reg
        }
    }
    __syncthreads();
    if (tid < 64)
        scores[row0 + tid] = red[tid] + red[64 + tid] + red[128 + tid] + red[192 + tid];
}

// ---------------------------------------------------------------------------
// softmax over T per batch. 64 blocks x 256 threads, 8 elems/thread.
// ---------------------------------------------------------------------------
__global__ void softmax_kernel(const float* __restrict__ scores, float* __restrict__ attn) {
    int b = blockIdx.x;
    int tid = threadIdx.x;
    __shared__ float red[4], red2[4];

    float s[8];
    float m = -1e30f;
    #pragma unroll
    for (int i = 0; i < 8; ++i) {
        s[i] = scores[b * T_DIM + i * 256 + tid];
        m = fmaxf(m, s[i]);
    }
    #pragma unroll
    for (int off = 1; off < 64; off <<= 1) m = fmaxf(m, __shfl_xor(m, off));
    if ((tid & 63) == 0) red[tid >> 6] = m;
    __syncthreads();
    m = fmaxf(fmaxf(red[0], red[1]), fmaxf(red[2], red[3]));

    float e[8], sum = 0.0f;
    #pragma unroll
    for (int i = 0; i < 8; ++i) {
        e[i] = exp2f((s[i] - m) * 1.44269504f);
        sum += e[i];
    }
    #pragma unroll
    for (int off = 1; off < 64; off <<= 1) sum += __shfl_xor(sum, off);
    if ((tid & 63) == 0) red2[tid >> 6] = sum;
    __syncthreads();
    sum = red2[0] + red2[1] + red2[2] + red2[3];
    float inv = 1.0f / sum;
    #pragma unroll
    for (int i = 0; i < 8; ++i)
        attn[b * T_DIM + i * 256 + tid] = e[i] * inv;
}

// ---------------------------------------------------------------------------
// context[b][d] = sum_t attn[b][t] * features[b][t][d]
// Grid (8, 64), block 256: block owns (b, 16 float4 columns) for ALL T.
// 16 t-partitions -> LDS reduce -> direct store. 2 blocks/CU.
// ---------------------------------------------------------------------------
__global__ void context_kernel(const float* __restrict__ attn,
                               const float* __restrict__ features,
                               float* __restrict__ out) {
    __shared__ float4 red[256];
    const int tid = threadIdx.x;
    const int b   = blockIdx.y;
    const int d4  = (blockIdx.x << 4) + (tid & 15);   // float4 column 0..127
    const int tp  = tid >> 4;                          // 0..15

    const float4* f  = reinterpret_cast<const float4*>(features) + (size_t)b * T_DIM * 128;
    const float*  ar = attn + b * T_DIM;

    float4 acc = {0.f, 0.f, 0.f, 0.f};
    #pragma unroll 8
    for (int i = 0; i < 128; ++i) {
        int t = tp * 128 + i;
        float a = ar[t];
        float4 v = f[(size_t)t * 128 + d4];
        acc.x = fmaf(a, v.x, acc.x);
        acc.y = fmaf(a, v.y, acc.y);
        acc.z = fmaf(a, v.z, acc.z);
        acc.w = fmaf(a, v.w, acc.w);
    }
    red[tid] = acc;
    __syncthreads();
    if (tp == 0) {
        float4 s = red[tid];
        #pragma unroll
        for (int j = 1; j < 16; ++j) {
            float4 v = red[tid + 16 * j];
            s.x += v.x; s.y += v.y; s.z += v.z; s.w += v.w;
        }
        reinterpret_cast<float4*>(out)[b * 128 + d4] = s;
    }
}

// ---------------------------------------------------------------------------
extern "C" void kernel_launch(void* const* d_in, const int* in_sizes, int n_in,
                              void* d_out, int out_size, void* d_ws, size_t ws_size,
                              hipStream_t stream) {
    const float* features = (const float*)d_in[0];
    const float* hidden   = (const float*)d_in[1];
    const float* W1w      = (const float*)d_in[2];
    const float* W1b      = (const float*)d_in[3];
    const float* W2w      = (const float*)d_in[4];
    const float* W2b      = (const float*)d_in[5];
    const float* Vw       = (const float*)d_in[6];
    // V_b cancels in softmax — unused.

    char* ws = (char*)d_ws;
    __bf16* w1c    = (__bf16*)ws;                      // 512 KiB
    float*  scores = (float*)(ws + (512u << 10));      // 512 KiB
    float*  attn   = (float*)(ws + (1024u << 10));     // 512 KiB
    float*  hp     = (float*)(ws + (1536u << 10));     // 128 KiB

    hipLaunchKernelGGL(w1c_kernel, dim3(128), dim3(256), 0, stream, W1w, w1c);
    hipLaunchKernelGGL(hproj_kernel, dim3(B_DIM, 2), dim3(256), 0, stream,
                       hidden, W2w, W2b, W1b, hp);
    hipLaunchKernelGGL(score_kernel, dim3(2048), dim3(256), 0, stream,
                       features, w1c, hp, Vw, scores);
    hipLaunchKernelGGL(softmax_kernel, dim3(B_DIM), dim3(256), 0, stream, scores, attn);
    hipLaunchKernelGGL(context_kernel, dim3(8, B_DIM), dim3(256), 0, stream,
                       attn, features, (float*)d_out);
}